// Round 8
// baseline (256.059 us; speedup 1.0000x reference)
//
#include <hip/hip_runtime.h>
#include <hip/hip_bf16.h>

#define BATCH 16
#define SEQ   4096
#define DH    64
#define KVB   64                // kv rows per tile
#define NT    (SEQ / KVB)       // 64 tiles
#define LDK   72                // padded LDS stride for tr_v prepass

using frag  = __attribute__((ext_vector_type(8))) short;           // 8 bf16
using f32x4 = __attribute__((ext_vector_type(4))) float;
using u16x8 = __attribute__((ext_vector_type(8))) unsigned short;
using u32x2 = __attribute__((ext_vector_type(2))) unsigned int;
using u32x4 = __attribute__((ext_vector_type(4))) unsigned int;

__device__ __forceinline__ unsigned short f2bf(float x) {
    union { __hip_bfloat16 h; unsigned short u; } cv;
    cv.h = __float2bfloat16(x);
    return cv.u;
}
__device__ __forceinline__ unsigned int pk2bf(float lo, float hi) {
    return (unsigned int)f2bf(lo) | ((unsigned int)f2bf(hi) << 16);
}

// ---------- pre-pass 1: K fp32 -> bf16 (same layout) ----------
__global__ __launch_bounds__(256) void cvt_k(const float* __restrict__ K,
                                             unsigned short* __restrict__ Kb) {
    const size_t i = ((size_t)blockIdx.x * 256 + threadIdx.x) * 8;
    float4 a = *(const float4*)(K + i);
    float4 b = *(const float4*)(K + i + 4);
    u16x8 o;
    o[0]=f2bf(a.x); o[1]=f2bf(a.y); o[2]=f2bf(a.z); o[3]=f2bf(a.w);
    o[4]=f2bf(b.x); o[5]=f2bf(b.y); o[6]=f2bf(b.z); o[7]=f2bf(b.w);
    *(u16x8*)(Kb + i) = o;
}

// ---------- pre-pass 2: V fp32 [b][kv][d] -> bf16 transposed [b][d][kv] ----------
__global__ __launch_bounds__(256) void tr_v(const float* __restrict__ V,
                                            unsigned short* __restrict__ Vt) {
    __shared__ unsigned short Ls[64 * LDK];
    const int b   = blockIdx.x >> 6;
    const int t64 = blockIdx.x & 63;
    const int t   = threadIdx.x;
    {
        const int kv = t >> 2, db = t & 3;
        const float* src = V + ((size_t)b * SEQ + (size_t)t64 * 64 + kv) * DH + db * 16;
        float4 a = *(const float4*)(src);
        float4 c = *(const float4*)(src + 4);
        float4 d = *(const float4*)(src + 8);
        float4 e = *(const float4*)(src + 12);
        u16x8 w0, w1;
        w0[0]=f2bf(a.x); w0[1]=f2bf(a.y); w0[2]=f2bf(a.z); w0[3]=f2bf(a.w);
        w0[4]=f2bf(c.x); w0[5]=f2bf(c.y); w0[6]=f2bf(c.z); w0[7]=f2bf(c.w);
        w1[0]=f2bf(d.x); w1[1]=f2bf(d.y); w1[2]=f2bf(d.z); w1[3]=f2bf(d.w);
        w1[4]=f2bf(e.x); w1[5]=f2bf(e.y); w1[6]=f2bf(e.z); w1[7]=f2bf(e.w);
        *(u16x8*)&Ls[kv * LDK + db * 16]     = w0;
        *(u16x8*)&Ls[kv * LDK + db * 16 + 8] = w1;
    }
    __syncthreads();
    {
        const int d = t >> 2, kb = t & 3;
        u16x8 o0, o1;
#pragma unroll
        for (int i = 0; i < 8; ++i) o0[i] = Ls[(kb * 16 + i) * LDK + d];
#pragma unroll
        for (int i = 0; i < 8; ++i) o1[i] = Ls[(kb * 16 + 8 + i) * LDK + d];
        unsigned short* dst = Vt + ((size_t)b * DH + d) * SEQ + (size_t)t64 * 64 + kb * 16;
        *(u16x8*)dst       = o0;
        *(u16x8*)(dst + 8) = o1;
    }
}

// ---------- main attention kernel ----------
// No LDS staging, no per-tile barriers: K/V fragments load straight from
// global (bf16 / pre-transposed bf16) as b128s -- KV working set is L2-resident.
// 2 waves per block split the kv range (even/odd tiles); partials merge via
// LDS at the end. LDS in the main loop is ONLY the per-wave P exchange.
// Swapped QK^T (lane owns its q-row), static-max exp2, ones-MFMA row-sum.
__global__ __launch_bounds__(128) void attn_fwd(
    const float* __restrict__ Q, const unsigned short* __restrict__ Kb,
    const unsigned short* __restrict__ Vtb, const float* __restrict__ S,
    float* __restrict__ O)
{
    __shared__ unsigned int SH[2 * 2 * 64 * 12];   // P-exchange [wave][qb]; reused as merge buf

    // 2048 blocks = 8 xcd * 2 batch * 128 qtile (bijective)
    const int bid   = blockIdx.x;
    const int xcd   = bid & 7;
    const int sub   = bid >> 3;                    // 0..255
    const int batch = xcd + ((sub & 1) << 3);
    const int qtile = sub >> 1;                    // 0..127, 32 q rows each

    const int tid  = threadIdx.x;
    const int h    = tid >> 6;                     // wave 0/1: even/odd kv tiles
    const int lane = tid & 63;
    const int c = lane & 15;
    const int g = lane >> 4;

    const float sc = S[0] * 1.44269504088896340736f;

    const float*          Qb = Q   + ((size_t)batch * SEQ + (size_t)qtile * 32) * DH;
    const unsigned short* Kg = Kb  + (size_t)batch * SEQ * DH;
    const unsigned short* Vg = Vtb + (size_t)batch * DH * SEQ;

    // Q B-frags (pre-scaled): lane holds q-row qb*16+c
    frag qB[2][2];
#pragma unroll
    for (int qb = 0; qb < 2; ++qb)
#pragma unroll
      for (int ks = 0; ks < 2; ++ks) {
        const float* p = Qb + (qb * 16 + c) * DH + ks * 32 + g * 8;
        float4 a = *(const float4*)p;
        float4 b = *(const float4*)(p + 4);
        frag f;
        f[0] = (short)f2bf(a.x * sc); f[1] = (short)f2bf(a.y * sc);
        f[2] = (short)f2bf(a.z * sc); f[3] = (short)f2bf(a.w * sc);
        f[4] = (short)f2bf(b.x * sc); f[5] = (short)f2bf(b.y * sc);
        f[6] = (short)f2bf(b.z * sc); f[7] = (short)f2bf(b.w * sc);
        qB[qb][ks] = f;
      }

    frag ones;
#pragma unroll
    for (int j = 0; j < 8; ++j) ones[j] = (short)0x3F80;

    f32x4 o_acc[2][4];
#pragma unroll
    for (int qb = 0; qb < 2; ++qb)
#pragma unroll
      for (int dt = 0; dt < 4; ++dt) o_acc[qb][dt] = (f32x4)0.0f;
    f32x4 l_acc[2] = {(f32x4)0.0f, (f32x4)0.0f};

    // P-exchange addressing (dword offsets, stride 12/lane)
    unsigned int* Pq[2] = { &SH[(h * 2 + 0) * 64 * 12], &SH[(h * 2 + 1) * 64 * 12] };
    const int base01 = (c + 32 * (g & 1)) * 12;
    const int base23 = base01 + 16 * 12;
    const int nt0    = g >> 1;

    for (int t = h; t < NT; t += 2) {
        // ---- K frags direct from global ----
        const unsigned short* Kt = Kg + (size_t)t * KVB * DH;
        frag kf[2][4];
#pragma unroll
        for (int ks = 0; ks < 2; ++ks)
#pragma unroll
          for (int nt = 0; nt < 4; ++nt)
            kf[ks][nt] = *(const frag*)(Kt + (nt * 16 + c) * DH + ks * 32 + g * 8);

        // ---- QK^T (swapped): st[qb][nt][r] = S[q=qb*16+c][kv=16nt+4g+r] ----
        f32x4 st[2][4];
#pragma unroll
        for (int qb = 0; qb < 2; ++qb)
#pragma unroll
          for (int nt = 0; nt < 4; ++nt) st[qb][nt] = (f32x4)0.0f;
#pragma unroll
        for (int ks = 0; ks < 2; ++ks)
#pragma unroll
          for (int nt = 0; nt < 4; ++nt) {
            st[0][nt] = __builtin_amdgcn_mfma_f32_16x16x32_bf16(kf[ks][nt], qB[0][ks], st[0][nt], 0, 0, 0);
            st[1][nt] = __builtin_amdgcn_mfma_f32_16x16x32_bf16(kf[ks][nt], qB[1][ks], st[1][nt], 0, 0, 0);
          }

        // ---- V frags (issued here so latency hides under exp/exchange) ----
        const unsigned short* Vt0 = Vg + (size_t)t * KVB;
        frag vf[2][4];
#pragma unroll
        for (int ks = 0; ks < 2; ++ks)
#pragma unroll
          for (int dt = 0; dt < 4; ++dt)
            vf[ks][dt] = *(const frag*)(Vt0 + (size_t)(dt * 16 + c) * SEQ + ks * 32 + g * 8);

        // ---- exp2 + pack + per-wave exchange -> PV A-frags ----
        frag pa[2][2];
#pragma unroll
        for (int qb = 0; qb < 2; ++qb) {
            unsigned int* myP = Pq[qb] + lane * 12;
            u32x4 dlo, dhi;
#pragma unroll
            for (int nt = 0; nt < 2; ++nt) {
                dlo[nt*2+0] = pk2bf(exp2f(st[qb][nt][0]), exp2f(st[qb][nt][1]));
                dlo[nt*2+1] = pk2bf(exp2f(st[qb][nt][2]), exp2f(st[qb][nt][3]));
            }
#pragma unroll
            for (int nt = 0; nt < 2; ++nt) {
                dhi[nt*2+0] = pk2bf(exp2f(st[qb][nt+2][0]), exp2f(st[qb][nt+2][1]));
                dhi[nt*2+1] = pk2bf(exp2f(st[qb][nt+2][2]), exp2f(st[qb][nt+2][3]));
            }
            *(u32x4*)(myP)     = dlo;
            *(u32x4*)(myP + 4) = dhi;
#pragma unroll
            for (int ks = 0; ks < 2; ++ks) {
                u32x2 a = *(const u32x2*)(Pq[qb] + base01 + (2 * ks + nt0) * 2);
                u32x2 b = *(const u32x2*)(Pq[qb] + base23 + (2 * ks + nt0) * 2);
                union { unsigned int u[4]; frag f; } fb;
                fb.u[0] = a[0]; fb.u[1] = a[1]; fb.u[2] = b[0]; fb.u[3] = b[1];
                pa[qb][ks] = fb.f;   // A[m=q=c][k=kv=32ks+8g+j]
            }
        }

        // ---- row-sum (ones-MFMA) + PV ----
#pragma unroll
        for (int ks = 0; ks < 2; ++ks) {
            l_acc[0] = __builtin_amdgcn_mfma_f32_16x16x32_bf16(pa[0][ks], ones, l_acc[0], 0, 0, 0);
            l_acc[1] = __builtin_amdgcn_mfma_f32_16x16x32_bf16(pa[1][ks], ones, l_acc[1], 0, 0, 0);
#pragma unroll
            for (int dt = 0; dt < 4; ++dt) {
                o_acc[0][dt] = __builtin_amdgcn_mfma_f32_16x16x32_bf16(pa[0][ks], vf[ks][dt], o_acc[0][dt], 0, 0, 0);
                o_acc[1][dt] = __builtin_amdgcn_mfma_f32_16x16x32_bf16(pa[1][ks], vf[ks][dt], o_acc[1][dt], 0, 0, 0);
            }
        }
    }

    // ---- merge the two kv-half partials, then store ----
    __syncthreads();                       // both waves done with P regions
    float* M = (float*)SH;                 // 2048 floats O-partial + 32 floats l-partial
    if (h == 1) {
#pragma unroll
        for (int qb = 0; qb < 2; ++qb) {
#pragma unroll
            for (int dt = 0; dt < 4; ++dt)
#pragma unroll
              for (int r = 0; r < 4; ++r)
                M[(qb * 16 + 4 * g + r) * DH + dt * 16 + c] = o_acc[qb][dt][r];
            if (c == 0)
#pragma unroll
              for (int r = 0; r < 4; ++r)
                M[2048 + qb * 16 + 4 * g + r] = l_acc[qb][r];
        }
    }
    __syncthreads();
    if (h == 0) {
        float* Ob = O + ((size_t)batch * SEQ + (size_t)qtile * 32) * DH;
#pragma unroll
        for (int qb = 0; qb < 2; ++qb) {
            f32x4 inv;
#pragma unroll
            for (int r = 0; r < 4; ++r)
                inv[r] = 1.0f / (l_acc[qb][r] + M[2048 + qb * 16 + 4 * g + r]);
#pragma unroll
            for (int dt = 0; dt < 4; ++dt)
#pragma unroll
              for (int r = 0; r < 4; ++r) {
                const int row = qb * 16 + 4 * g + r;
                Ob[row * DH + dt * 16 + c] =
                    (o_acc[qb][dt][r] + M[row * DH + dt * 16 + c]) * inv[r];
              }
        }
    }
}

extern "C" void kernel_launch(void* const* d_in, const int* in_sizes, int n_in,
                              void* d_out, int out_size, void* d_ws, size_t ws_size,
                              hipStream_t stream) {
    const float* q = (const float*)d_in[0];
    const float* k = (const float*)d_in[1];
    const float* v = (const float*)d_in[2];
    const float* s = (const float*)d_in[3];
    float* o = (float*)d_out;

    unsigned short* kb = (unsigned short*)d_ws;
    unsigned short* vt = kb + (size_t)BATCH * SEQ * DH;

    const int cvt_blocks = (BATCH * SEQ * DH) / (256 * 8);
    cvt_k<<<dim3(cvt_blocks), dim3(256), 0, stream>>>(k, kb);
    tr_v<<<dim3(BATCH * (SEQ / 64)), dim3(256), 0, stream>>>(v, vt);

    const int blocks = BATCH * (SEQ / 32);  // 2048: one 32-row q-tile per block
    attn_fwd<<<dim3(blocks), dim3(128), 0, stream>>>(q, kb, vt, s, o);
}

// Round 10
// 145.521 us; speedup vs baseline: 1.7596x; 1.7596x over previous
//
#include <hip/hip_runtime.h>
#include <hip/hip_bf16.h>

#define BATCH 16
#define SEQ   4096
#define DH    64
#define KVB   64                // kv rows per tile
#define NT    (SEQ / KVB)       // 64 tiles
#define LDK   72                // padded LDS row stride (bf16 elems)

using frag  = __attribute__((ext_vector_type(8))) short;           // 8 bf16
using f32x4 = __attribute__((ext_vector_type(4))) float;
using u16x8 = __attribute__((ext_vector_type(8))) unsigned short;
using u32x2 = __attribute__((ext_vector_type(2))) unsigned int;
using u32x4 = __attribute__((ext_vector_type(4))) unsigned int;

__device__ __forceinline__ unsigned short f2bf(float x) {
    union { __hip_bfloat16 h; unsigned short u; } cv;
    cv.h = __float2bfloat16(x);
    return cv.u;
}
__device__ __forceinline__ unsigned int pk2bf(float lo, float hi) {
    return (unsigned int)f2bf(lo) | ((unsigned int)f2bf(hi) << 16);
}

// ---------- pre-pass 1: K fp32 -> bf16 (same layout) ----------
__global__ __launch_bounds__(256) void cvt_k(const float* __restrict__ K,
                                             unsigned short* __restrict__ Kb) {
    const size_t i = ((size_t)blockIdx.x * 256 + threadIdx.x) * 8;
    float4 a = *(const float4*)(K + i);
    float4 b = *(const float4*)(K + i + 4);
    u16x8 o;
    o[0]=f2bf(a.x); o[1]=f2bf(a.y); o[2]=f2bf(a.z); o[3]=f2bf(a.w);
    o[4]=f2bf(b.x); o[5]=f2bf(b.y); o[6]=f2bf(b.z); o[7]=f2bf(b.w);
    *(u16x8*)(Kb + i) = o;
}

// ---------- pre-pass 2: V fp32 [b][kv][d] -> bf16 transposed [b][d][kv] ----------
__global__ __launch_bounds__(256) void tr_v(const float* __restrict__ V,
                                            unsigned short* __restrict__ Vt) {
    __shared__ unsigned short Ls[64 * LDK];
    const int b   = blockIdx.x >> 6;
    const int t64 = blockIdx.x & 63;
    const int t   = threadIdx.x;
    {
        const int kv = t >> 2, db = t & 3;
        const float* src = V + ((size_t)b * SEQ + (size_t)t64 * 64 + kv) * DH + db * 16;
        float4 a = *(const float4*)(src);
        float4 c = *(const float4*)(src + 4);
        float4 d = *(const float4*)(src + 8);
        float4 e = *(const float4*)(src + 12);
        u16x8 w0, w1;
        w0[0]=f2bf(a.x); w0[1]=f2bf(a.y); w0[2]=f2bf(a.z); w0[3]=f2bf(a.w);
        w0[4]=f2bf(c.x); w0[5]=f2bf(c.y); w0[6]=f2bf(c.z); w0[7]=f2bf(c.w);
        w1[0]=f2bf(d.x); w1[1]=f2bf(d.y); w1[2]=f2bf(d.z); w1[3]=f2bf(d.w);
        w1[4]=f2bf(e.x); w1[5]=f2bf(e.y); w1[6]=f2bf(e.z); w1[7]=f2bf(e.w);
        *(u16x8*)&Ls[kv * LDK + db * 16]     = w0;
        *(u16x8*)&Ls[kv * LDK + db * 16 + 8] = w1;
    }
    __syncthreads();
    {
        const int d = t >> 2, kb = t & 3;
        u16x8 o0, o1;
#pragma unroll
        for (int i = 0; i < 8; ++i) o0[i] = Ls[(kb * 16 + i) * LDK + d];
#pragma unroll
        for (int i = 0; i < 8; ++i) o1[i] = Ls[(kb * 16 + 8 + i) * LDK + d];
        unsigned short* dst = Vt + ((size_t)b * DH + d) * SEQ + (size_t)t64 * 64 + kb * 16;
        *(u16x8*)dst       = o0;
        *(u16x8*)(dst + 8) = o1;
    }
}

// ---------- main attention kernel ----------
// 2-wave blocks, 4 independent blocks/CU (grid 1024): un-synchronized streams
// de-phase each other so LDS/VALU/MFMA phases overlap across blocks.
// Swapped QK^T (lane owns q-row c), packed P-exchange (per-wave buffer,
// time-shared across qb), static-max exp2, ones-MFMA row-sum.
__global__ __launch_bounds__(128, 2) void attn_fwd(
    const float* __restrict__ Q, const unsigned short* __restrict__ Kb,
    const unsigned short* __restrict__ Vtb, const float* __restrict__ S,
    float* __restrict__ O)
{
    __shared__ unsigned short Ks[KVB * LDK];      // K tile [kv][d]    9216 B
    __shared__ unsigned short Vs[DH * LDK];       // V tile [d][kv]    9216 B
    __shared__ unsigned int   Pbuf[2][64 * 12];   // per-wave exchange 6144 B

    // 1024 blocks = 8 xcd * 2 batch * 64 qtile (bijective)
    const int bid   = blockIdx.x;
    const int xcd   = bid & 7;
    const int sub   = bid >> 3;                     // 0..127
    const int batch = xcd + ((sub & 1) << 3);
    const int qtile = sub >> 1;                     // 0..63, 64 q rows each

    const int tid  = threadIdx.x;
    const int w    = tid >> 6;                      // wave 0/1, owns 32 q rows
    const int lane = tid & 63;
    const int c = lane & 15;
    const int g = lane >> 4;

    const float sc = S[0] * 1.44269504088896340736f;

    const float*          Qb = Q   + ((size_t)batch * SEQ + (size_t)qtile * 64 + w * 32) * DH;
    const unsigned short* Kg = Kb  + (size_t)batch * SEQ * DH;
    const unsigned short* Vg = Vtb + (size_t)batch * DH * SEQ;

    // Q B-frags (pre-scaled): lane holds q-row qb*16+c
    frag qB[2][2];
#pragma unroll
    for (int qb = 0; qb < 2; ++qb)
#pragma unroll
      for (int ks = 0; ks < 2; ++ks) {
        const float* p = Qb + (qb * 16 + c) * DH + ks * 32 + g * 8;
        float4 a = *(const float4*)p;
        float4 b = *(const float4*)(p + 4);
        frag f;
        f[0] = (short)f2bf(a.x * sc); f[1] = (short)f2bf(a.y * sc);
        f[2] = (short)f2bf(a.z * sc); f[3] = (short)f2bf(a.w * sc);
        f[4] = (short)f2bf(b.x * sc); f[5] = (short)f2bf(b.y * sc);
        f[6] = (short)f2bf(b.z * sc); f[7] = (short)f2bf(b.w * sc);
        qB[qb][ks] = f;
      }

    frag ones;
#pragma unroll
    for (int j = 0; j < 8; ++j) ones[j] = (short)0x3F80;

    f32x4 o_acc[2][4];
#pragma unroll
    for (int qb = 0; qb < 2; ++qb)
#pragma unroll
      for (int dt = 0; dt < 4; ++dt) o_acc[qb][dt] = (f32x4)0.0f;
    f32x4 l_acc[2] = {(f32x4)0.0f, (f32x4)0.0f};

    // staging: 128 threads; thread t copies 64B (32 elems) of K and of V per
    // tile as FOUR contiguous u16x8 loads (offsets 0,8,16,24).
    const int srow = tid >> 1;                  // 0..63
    const int scol = (tid & 1) << 5;            // 0 or 32 (elems)
    const unsigned short* ksrc = Kg + srow * DH + scol;
    const unsigned short* vsrc = Vg + (size_t)srow * SEQ + scol;
    unsigned short* kdst = &Ks[srow * LDK + scol];
    unsigned short* vdst = &Vs[srow * LDK + scol];

    u16x8 kp0 = *(const u16x8*)ksrc,        kp1 = *(const u16x8*)(ksrc + 8);
    u16x8 kp2 = *(const u16x8*)(ksrc + 16), kp3 = *(const u16x8*)(ksrc + 24);
    u16x8 vp0 = *(const u16x8*)vsrc,        vp1 = *(const u16x8*)(vsrc + 8);
    u16x8 vp2 = *(const u16x8*)(vsrc + 16), vp3 = *(const u16x8*)(vsrc + 24);

    // P-exchange read addressing (dword offsets), per-wave buffer
    unsigned int* Pw = &Pbuf[w][0];
    const int base01 = (c + 32 * (g & 1)) * 12;
    const int base23 = base01 + 16 * 12;
    const int nt0    = g >> 1;

    for (int t = 0; t < NT; ++t) {
        __syncthreads();
        *(u16x8*)kdst        = kp0;  *(u16x8*)(kdst + 8)  = kp1;
        *(u16x8*)(kdst + 16) = kp2;  *(u16x8*)(kdst + 24) = kp3;
        *(u16x8*)vdst        = vp0;  *(u16x8*)(vdst + 8)  = vp1;
        *(u16x8*)(vdst + 16) = vp2;  *(u16x8*)(vdst + 24) = vp3;
        __syncthreads();
        if (t + 1 < NT) {
            const unsigned short* kp = ksrc + (size_t)(t + 1) * KVB * DH;
            const unsigned short* vp = vsrc + (size_t)(t + 1) * KVB;
            kp0 = *(const u16x8*)kp;        kp1 = *(const u16x8*)(kp + 8);
            kp2 = *(const u16x8*)(kp + 16); kp3 = *(const u16x8*)(kp + 24);
            vp0 = *(const u16x8*)vp;        vp1 = *(const u16x8*)(vp + 8);
            vp2 = *(const u16x8*)(vp + 16); vp3 = *(const u16x8*)(vp + 24);
        }

        // ---- QK^T (swapped): st[qb][nt][r] = S[q=qb*16+c][kv=16nt+4g+r] ----
        f32x4 st[2][4];
#pragma unroll
        for (int qb = 0; qb < 2; ++qb)
#pragma unroll
          for (int nt = 0; nt < 4; ++nt) st[qb][nt] = (f32x4)0.0f;
        __builtin_amdgcn_s_setprio(1);
#pragma unroll
        for (int ks = 0; ks < 2; ++ks)
#pragma unroll
          for (int nt = 0; nt < 4; ++nt) {
            frag kf = *(const frag*)&Ks[(nt * 16 + c) * LDK + ks * 32 + g * 8];
            st[0][nt] = __builtin_amdgcn_mfma_f32_16x16x32_bf16(kf, qB[0][ks], st[0][nt], 0, 0, 0);
            st[1][nt] = __builtin_amdgcn_mfma_f32_16x16x32_bf16(kf, qB[1][ks], st[1][nt], 0, 0, 0);
          }
        __builtin_amdgcn_s_setprio(0);

        // ---- V frags hoisted: ds_read latency hides under exp/exchange ----
        frag vf[2][4];
#pragma unroll
        for (int ks = 0; ks < 2; ++ks)
#pragma unroll
          for (int dt = 0; dt < 4; ++dt)
            vf[ks][dt] = *(const frag*)&Vs[(dt * 16 + c) * LDK + ks * 32 + g * 8];

        // ---- exp2 + pack + per-wave exchange -> PV A-frags ----
        // (qb passes time-share Pw; per-wave DS ordering makes this safe)
        frag pa[2][2];
#pragma unroll
        for (int qb = 0; qb < 2; ++qb) {
            unsigned int* myP = Pw + lane * 12;
            u32x4 dlo, dhi;
#pragma unroll
            for (int nt = 0; nt < 2; ++nt) {
                dlo[nt*2+0] = pk2bf(exp2f(st[qb][nt][0]), exp2f(st[qb][nt][1]));
                dlo[nt*2+1] = pk2bf(exp2f(st[qb][nt][2]), exp2f(st[qb][nt][3]));
            }
#pragma unroll
            for (int nt = 0; nt < 2; ++nt) {
                dhi[nt*2+0] = pk2bf(exp2f(st[qb][nt+2][0]), exp2f(st[qb][nt+2][1]));
                dhi[nt*2+1] = pk2bf(exp2f(st[qb][nt+2][2]), exp2f(st[qb][nt+2][3]));
            }
            *(u32x4*)(myP)     = dlo;
            *(u32x4*)(myP + 4) = dhi;
#pragma unroll
            for (int ks = 0; ks < 2; ++ks) {
                u32x2 a = *(const u32x2*)(Pw + base01 + (2 * ks + nt0) * 2);
                u32x2 b = *(const u32x2*)(Pw + base23 + (2 * ks + nt0) * 2);
                union { unsigned int u[4]; frag f; } fb;
                fb.u[0] = a[0]; fb.u[1] = a[1]; fb.u[2] = b[0]; fb.u[3] = b[1];
                pa[qb][ks] = fb.f;   // A[m=q=c][k=kv=32ks+8g+j]
            }
        }

        // ---- row-sum (ones-MFMA) + PV ----
        __builtin_amdgcn_s_setprio(1);
#pragma unroll
        for (int ks = 0; ks < 2; ++ks) {
            l_acc[0] = __builtin_amdgcn_mfma_f32_16x16x32_bf16(pa[0][ks], ones, l_acc[0], 0, 0, 0);
            l_acc[1] = __builtin_amdgcn_mfma_f32_16x16x32_bf16(pa[1][ks], ones, l_acc[1], 0, 0, 0);
#pragma unroll
            for (int dt = 0; dt < 4; ++dt) {
                o_acc[0][dt] = __builtin_amdgcn_mfma_f32_16x16x32_bf16(pa[0][ks], vf[ks][dt], o_acc[0][dt], 0, 0, 0);
                o_acc[1][dt] = __builtin_amdgcn_mfma_f32_16x16x32_bf16(pa[1][ks], vf[ks][dt], o_acc[1][dt], 0, 0, 0);
            }
        }
        __builtin_amdgcn_s_setprio(0);
    }

    // ---- epilogue: rows q = qb*16 + 4g + r, cols d = dt*16 + c ----
    float* Ob = O + ((size_t)batch * SEQ + (size_t)qtile * 64 + w * 32) * DH;
#pragma unroll
    for (int qb = 0; qb < 2; ++qb) {
        f32x4 inv;
#pragma unroll
        for (int r = 0; r < 4; ++r) inv[r] = 1.0f / l_acc[qb][r];
#pragma unroll
        for (int dt = 0; dt < 4; ++dt)
#pragma unroll
          for (int r = 0; r < 4; ++r)
            Ob[(qb * 16 + 4 * g + r) * DH + dt * 16 + c] = o_acc[qb][dt][r] * inv[r];
    }
}

extern "C" void kernel_launch(void* const* d_in, const int* in_sizes, int n_in,
                              void* d_out, int out_size, void* d_ws, size_t ws_size,
                              hipStream_t stream) {
    const float* q = (const float*)d_in[0];
    const float* k = (const float*)d_in[1];
    const float* v = (const float*)d_in[2];
    const float* s = (const float*)d_in[3];
    float* o = (float*)d_out;

    unsigned short* kb = (unsigned short*)d_ws;
    unsigned short* vt = kb + (size_t)BATCH * SEQ * DH;

    const int cvt_blocks = (BATCH * SEQ * DH) / (256 * 8);
    cvt_k<<<dim3(cvt_blocks), dim3(256), 0, stream>>>(k, kb);
    tr_v<<<dim3(BATCH * (SEQ / 64)), dim3(256), 0, stream>>>(v, vt);

    const int blocks = BATCH * (SEQ / 64);  // 1024: 64-row q-tile per block
    attn_fwd<<<dim3(blocks), dim3(128), 0, stream>>>(q, kb, vt, s, o);
}

// Round 11
// 138.218 us; speedup vs baseline: 1.8526x; 1.0528x over previous
//
#include <hip/hip_runtime.h>
#include <hip/hip_bf16.h>

#define BATCH 16
#define SEQ   4096
#define DH    64
#define KVB   64                // kv rows per tile
#define NT    (SEQ / KVB)       // 64 tiles
#define LDK   72                // padded LDS row stride (bf16 elems)

using frag   = __attribute__((ext_vector_type(8))) short;           // 8 bf16
using f32x16 = __attribute__((ext_vector_type(16))) float;
using u16x8  = __attribute__((ext_vector_type(8))) unsigned short;

__device__ __forceinline__ unsigned short f2bf(float x) {
    union { __hip_bfloat16 h; unsigned short u; } cv;
    cv.h = __float2bfloat16(x);
    return cv.u;
}
__device__ __forceinline__ unsigned int pk2bf(float lo, float hi) {
    return (unsigned int)f2bf(lo) | ((unsigned int)f2bf(hi) << 16);
}

// ---------- pre-pass 1: K fp32 -> bf16 (same layout) ----------
__global__ __launch_bounds__(256) void cvt_k(const float* __restrict__ K,
                                             unsigned short* __restrict__ Kb) {
    const size_t i = ((size_t)blockIdx.x * 256 + threadIdx.x) * 8;
    float4 a = *(const float4*)(K + i);
    float4 b = *(const float4*)(K + i + 4);
    u16x8 o;
    o[0]=f2bf(a.x); o[1]=f2bf(a.y); o[2]=f2bf(a.z); o[3]=f2bf(a.w);
    o[4]=f2bf(b.x); o[5]=f2bf(b.y); o[6]=f2bf(b.z); o[7]=f2bf(b.w);
    *(u16x8*)(Kb + i) = o;
}

// ---------- pre-pass 2: V fp32 [b][kv][d] -> bf16 transposed [b][d][kv] ----------
__global__ __launch_bounds__(256) void tr_v(const float* __restrict__ V,
                                            unsigned short* __restrict__ Vt) {
    __shared__ unsigned short Ls[64 * LDK];
    const int b   = blockIdx.x >> 6;
    const int t64 = blockIdx.x & 63;
    const int t   = threadIdx.x;
    {
        const int kv = t >> 2, db = t & 3;
        const float* src = V + ((size_t)b * SEQ + (size_t)t64 * 64 + kv) * DH + db * 16;
        float4 a = *(const float4*)(src);
        float4 c = *(const float4*)(src + 4);
        float4 d = *(const float4*)(src + 8);
        float4 e = *(const float4*)(src + 12);
        u16x8 w0, w1;
        w0[0]=f2bf(a.x); w0[1]=f2bf(a.y); w0[2]=f2bf(a.z); w0[3]=f2bf(a.w);
        w0[4]=f2bf(c.x); w0[5]=f2bf(c.y); w0[6]=f2bf(c.z); w0[7]=f2bf(c.w);
        w1[0]=f2bf(d.x); w1[1]=f2bf(d.y); w1[2]=f2bf(d.z); w1[3]=f2bf(d.w);
        w1[4]=f2bf(e.x); w1[5]=f2bf(e.y); w1[6]=f2bf(e.z); w1[7]=f2bf(e.w);
        *(u16x8*)&Ls[kv * LDK + db * 16]     = w0;
        *(u16x8*)&Ls[kv * LDK + db * 16 + 8] = w1;
    }
    __syncthreads();
    {
        const int d = t >> 2, kb = t & 3;
        u16x8 o0, o1;
#pragma unroll
        for (int i = 0; i < 8; ++i) o0[i] = Ls[(kb * 16 + i) * LDK + d];
#pragma unroll
        for (int i = 0; i < 8; ++i) o1[i] = Ls[(kb * 16 + 8 + i) * LDK + d];
        unsigned short* dst = Vt + ((size_t)b * DH + d) * SEQ + (size_t)t64 * 64 + kb * 16;
        *(u16x8*)dst       = o0;
        *(u16x8*)(dst + 8) = o1;
    }
}

// ---------- main attention kernel ----------
// 32x32x16 MFMAs. Swapped QK^T: C col = lane&31 = q --> each lane holds its
// q-row's P in REGISTERS (rows kv = (reg&3)+8*(reg>>2)+4*hi). P -> PV A-frag
// via 16 cvt_pk + 8 v_permlane32_swap (no P LDS at all). Static-max exp2,
// row-sum via all-ones-B MFMA (C rows match O's rows).
__global__ __launch_bounds__(128, 2) void attn_fwd(
    const float* __restrict__ Q, const unsigned short* __restrict__ Kb,
    const unsigned short* __restrict__ Vtb, const float* __restrict__ S,
    float* __restrict__ O)
{
    __shared__ unsigned short Ks[KVB * LDK];      // K tile [kv][d]  9216 B
    __shared__ unsigned short Vs[DH * LDK];       // V tile [d][kv]  9216 B

    // 1024 blocks = 8 xcd * 2 batch * 64 qtile (bijective)
    const int bid   = blockIdx.x;
    const int xcd   = bid & 7;
    const int sub   = bid >> 3;                     // 0..127
    const int batch = xcd + ((sub & 1) << 3);
    const int qtile = sub >> 1;                     // 0..63, 64 q rows each

    const int tid  = threadIdx.x;
    const int w    = tid >> 6;                      // wave 0/1, owns 32 q rows
    const int lane = tid & 63;
    const int c32  = lane & 31;                     // q-row (QK/PV A) / d-col (PV B)
    const int hi   = lane >> 5;

    const float sc = S[0] * 1.44269504088896340736f;

    const float*          Qb = Q   + ((size_t)batch * SEQ + (size_t)qtile * 64 + w * 32) * DH;
    const unsigned short* Kg = Kb  + (size_t)batch * SEQ * DH;
    const unsigned short* Vg = Vtb + (size_t)batch * DH * SEQ;

    // Q B-frags (pre-scaled): B[k=d][n=q]: lane holds q-row c32, d = kstep*16+hi*8+j
    frag qF[4];
#pragma unroll
    for (int kstep = 0; kstep < 4; ++kstep) {
        const float* p = Qb + c32 * DH + kstep * 16 + hi * 8;
        float4 a = *(const float4*)p;
        float4 b = *(const float4*)(p + 4);
        frag f;
        f[0] = (short)f2bf(a.x * sc); f[1] = (short)f2bf(a.y * sc);
        f[2] = (short)f2bf(a.z * sc); f[3] = (short)f2bf(a.w * sc);
        f[4] = (short)f2bf(b.x * sc); f[5] = (short)f2bf(b.y * sc);
        f[6] = (short)f2bf(b.z * sc); f[7] = (short)f2bf(b.w * sc);
        qF[kstep] = f;
    }

    frag ones;
#pragma unroll
    for (int j = 0; j < 8; ++j) ones[j] = (short)0x3F80;   // bf16 1.0

    f32x16 o32[2];                  // O: col d = dblk*32+c32, row q = (reg&3)+8*(reg>>2)+4*hi
    f32x16 l32;                     // row-sums, same row mapping
    o32[0] = (f32x16)0.0f; o32[1] = (f32x16)0.0f; l32 = (f32x16)0.0f;

    // staging: 128 threads; thread copies 64B (32 elems) of K and of V per tile
    const int srow = tid >> 1;                  // 0..63
    const int scol = (tid & 1) << 5;            // 0 or 32 (elems)
    const unsigned short* ksrc = Kg + srow * DH + scol;
    const unsigned short* vsrc = Vg + (size_t)srow * SEQ + scol;
    unsigned short* kdst = &Ks[srow * LDK + scol];
    unsigned short* vdst = &Vs[srow * LDK + scol];

    u16x8 kp0 = *(const u16x8*)ksrc,        kp1 = *(const u16x8*)(ksrc + 8);
    u16x8 kp2 = *(const u16x8*)(ksrc + 16), kp3 = *(const u16x8*)(ksrc + 24);
    u16x8 vp0 = *(const u16x8*)vsrc,        vp1 = *(const u16x8*)(vsrc + 8);
    u16x8 vp2 = *(const u16x8*)(vsrc + 16), vp3 = *(const u16x8*)(vsrc + 24);

    for (int t = 0; t < NT; ++t) {
        __syncthreads();
        *(u16x8*)kdst        = kp0;  *(u16x8*)(kdst + 8)  = kp1;
        *(u16x8*)(kdst + 16) = kp2;  *(u16x8*)(kdst + 24) = kp3;
        *(u16x8*)vdst        = vp0;  *(u16x8*)(vdst + 8)  = vp1;
        *(u16x8*)(vdst + 16) = vp2;  *(u16x8*)(vdst + 24) = vp3;
        __syncthreads();
        if (t + 1 < NT) {
            const unsigned short* kp = ksrc + (size_t)(t + 1) * KVB * DH;
            const unsigned short* vp = vsrc + (size_t)(t + 1) * KVB;
            kp0 = *(const u16x8*)kp;        kp1 = *(const u16x8*)(kp + 8);
            kp2 = *(const u16x8*)(kp + 16); kp3 = *(const u16x8*)(kp + 24);
            vp0 = *(const u16x8*)vp;        vp1 = *(const u16x8*)(vp + 8);
            vp2 = *(const u16x8*)(vp + 16); vp3 = *(const u16x8*)(vp + 24);
        }

        // ---- QK^T (swapped, 32x32x16): st[kb] = S^T[kv=kb*32+..][q=c32] ----
        f32x16 st[2];
        st[0] = (f32x16)0.0f; st[1] = (f32x16)0.0f;
        __builtin_amdgcn_s_setprio(1);
#pragma unroll
        for (int kstep = 0; kstep < 4; ++kstep) {
#pragma unroll
            for (int kb = 0; kb < 2; ++kb) {
                frag kf = *(const frag*)&Ks[(kb * 32 + c32) * LDK + kstep * 16 + hi * 8];
                st[kb] = __builtin_amdgcn_mfma_f32_32x32x16_bf16(kf, qF[kstep], st[kb], 0, 0, 0);
            }
        }
        __builtin_amdgcn_s_setprio(0);

        // ---- exp2 + cvt_pk + permlane32_swap -> PV A-frags (no LDS!) ----
        // lane's P values: kv = kb*32 + (reg&3) + 8*(reg>>2) + 4*hi, its q-row = c32
        frag pa[2][2];
#pragma unroll
        for (int kb = 0; kb < 2; ++kb) {
            float p[16];
#pragma unroll
            for (int r = 0; r < 16; ++r) p[r] = exp2f(st[kb][r]);
            unsigned a0 = pk2bf(p[0],  p[1]),  a1 = pk2bf(p[2],  p[3]);
            unsigned b0 = pk2bf(p[4],  p[5]),  b1 = pk2bf(p[6],  p[7]);
            unsigned c0 = pk2bf(p[8],  p[9]),  c1 = pk2bf(p[10], p[11]);
            unsigned d0 = pk2bf(p[12], p[13]), d1 = pk2bf(p[14], p[15]);
            asm("v_permlane32_swap_b32 %0, %1" : "+v"(a0), "+v"(b0));
            asm("v_permlane32_swap_b32 %0, %1" : "+v"(a1), "+v"(b1));
            asm("v_permlane32_swap_b32 %0, %1" : "+v"(c0), "+v"(d0));
            asm("v_permlane32_swap_b32 %0, %1" : "+v"(c1), "+v"(d1));
            union { unsigned u[4]; frag f; } f0, f1;
            f0.u[0] = a0; f0.u[1] = a1; f0.u[2] = b0; f0.u[3] = b1;   // kv ks=0..15
            f1.u[0] = c0; f1.u[1] = c1; f1.u[2] = d0; f1.u[3] = d1;   // kv 16..31
            pa[kb][0] = f0.f;
            pa[kb][1] = f1.f;
        }

        // ---- row-sum (ones-MFMA) + PV ----
        __builtin_amdgcn_s_setprio(1);
#pragma unroll
        for (int kb = 0; kb < 2; ++kb)
#pragma unroll
          for (int ks = 0; ks < 2; ++ks) {
            l32 = __builtin_amdgcn_mfma_f32_32x32x16_bf16(pa[kb][ks], ones, l32, 0, 0, 0);
#pragma unroll
            for (int dblk = 0; dblk < 2; ++dblk) {
                frag vf = *(const frag*)&Vs[(dblk * 32 + c32) * LDK + kb * 32 + ks * 16 + hi * 8];
                o32[dblk] = __builtin_amdgcn_mfma_f32_32x32x16_bf16(pa[kb][ks], vf, o32[dblk], 0, 0, 0);
            }
          }
        __builtin_amdgcn_s_setprio(0);
    }

    // ---- epilogue: row q = (reg&3)+8*(reg>>2)+4*hi, col d = dblk*32+c32 ----
    float* Ob = O + ((size_t)batch * SEQ + (size_t)qtile * 64 + w * 32) * DH;
    float inv[16];
#pragma unroll
    for (int r = 0; r < 16; ++r) inv[r] = 1.0f / l32[r];
#pragma unroll
    for (int dblk = 0; dblk < 2; ++dblk)
#pragma unroll
      for (int r = 0; r < 16; ++r) {
        const int qrow = (r & 3) + 8 * (r >> 2) + 4 * hi;
        Ob[qrow * DH + dblk * 32 + c32] = o32[dblk][r] * inv[r];
      }
}

extern "C" void kernel_launch(void* const* d_in, const int* in_sizes, int n_in,
                              void* d_out, int out_size, void* d_ws, size_t ws_size,
                              hipStream_t stream) {
    const float* q = (const float*)d_in[0];
    const float* k = (const float*)d_in[1];
    const float* v = (const float*)d_in[2];
    const float* s = (const float*)d_in[3];
    float* o = (float*)d_out;

    unsigned short* kb = (unsigned short*)d_ws;
    unsigned short* vt = kb + (size_t)BATCH * SEQ * DH;

    const int cvt_blocks = (BATCH * SEQ * DH) / (256 * 8);
    cvt_k<<<dim3(cvt_blocks), dim3(256), 0, stream>>>(k, kb);
    tr_v<<<dim3(BATCH * (SEQ / 64)), dim3(256), 0, stream>>>(v, vt);

    const int blocks = BATCH * (SEQ / 64);  // 1024: 64-row q-tile per block
    attn_fwd<<<dim3(blocks), dim3(128), 0, stream>>>(q, kb, vt, s, o);
}